// Round 1
// baseline (63.639 us; speedup 1.0000x reference)
//
#include <hip/hip_runtime.h>

#define BATCH 16384
#define FDIM 256

__global__ __launch_bounds__(256) void center_loss_kernel(
    const float* __restrict__ feat,
    const int* __restrict__ labels,
    const float* __restrict__ centers,
    float* __restrict__ out)
{
    // One wave (64 lanes) per row; 4 rows per 256-thread block.
    const int wave_in_block = threadIdx.x >> 6;
    const int lane = threadIdx.x & 63;
    const int row = blockIdx.x * 4 + wave_in_block;

    // row < BATCH always: grid sized exactly BATCH/4.
    const int label = labels[row];

    const float4* frow = reinterpret_cast<const float4*>(feat + (size_t)row * FDIM);
    const float4* crow = reinterpret_cast<const float4*>(centers + (size_t)label * FDIM);

    float4 fv = frow[lane];
    float4 cv = crow[lane];

    float dx = fv.x - cv.x;
    float dy = fv.y - cv.y;
    float dz = fv.z - cv.z;
    float dw = fv.w - cv.w;
    float s = dx * dx + dy * dy + dz * dz + dw * dw;

    // Wave-level reduction across 64 lanes.
    #pragma unroll
    for (int off = 32; off > 0; off >>= 1)
        s += __shfl_down(s, off, 64);

    __shared__ float wsum[4];
    if (lane == 0) wsum[wave_in_block] = s;
    __syncthreads();

    if (threadIdx.x == 0) {
        float t = (wsum[0] + wsum[1]) + (wsum[2] + wsum[3]);
        atomicAdd(out, t * (1.0f / (2.0f * BATCH)));
    }
}

extern "C" void kernel_launch(void* const* d_in, const int* in_sizes, int n_in,
                              void* d_out, int out_size, void* d_ws, size_t ws_size,
                              hipStream_t stream) {
    const float* feat    = (const float*)d_in[0];
    const int*   labels  = (const int*)d_in[1];
    const float* centers = (const float*)d_in[2];
    float* out = (float*)d_out;

    // d_out is poisoned once and never re-poisoned between timed replays;
    // we accumulate with atomics, so zero it every call (async, capture-safe).
    hipMemsetAsync(out, 0, sizeof(float), stream);

    const int blocks = BATCH / 4;  // 4096
    center_loss_kernel<<<blocks, 256, 0, stream>>>(feat, labels, centers, out);
}

// Round 2
// 15.935 us; speedup vs baseline: 3.9936x; 3.9936x over previous
//
#include <hip/hip_runtime.h>

#define BATCH 16384
#define FDIM 256
#define NBLOCKS (BATCH / 4)  // 4096 partial sums

__global__ __launch_bounds__(256) void center_loss_partial(
    const float* __restrict__ feat,
    const int* __restrict__ labels,
    const float* __restrict__ centers,
    float* __restrict__ partials)
{
    // One wave (64 lanes) per row; 4 rows per 256-thread block.
    const int wave_in_block = threadIdx.x >> 6;
    const int lane = threadIdx.x & 63;
    const int row = blockIdx.x * 4 + wave_in_block;

    const int label = labels[row];

    const float4* frow = reinterpret_cast<const float4*>(feat + (size_t)row * FDIM);
    const float4* crow = reinterpret_cast<const float4*>(centers + (size_t)label * FDIM);

    float4 fv = frow[lane];
    float4 cv = crow[lane];

    float dx = fv.x - cv.x;
    float dy = fv.y - cv.y;
    float dz = fv.z - cv.z;
    float dw = fv.w - cv.w;
    float s = dx * dx + dy * dy + dz * dz + dw * dw;

    // Wave-level reduction across 64 lanes.
    #pragma unroll
    for (int off = 32; off > 0; off >>= 1)
        s += __shfl_down(s, off, 64);

    __shared__ float wsum[4];
    if (lane == 0) wsum[wave_in_block] = s;
    __syncthreads();

    if (threadIdx.x == 0) {
        partials[blockIdx.x] = (wsum[0] + wsum[1]) + (wsum[2] + wsum[3]);
    }
}

__global__ __launch_bounds__(1024) void center_loss_final(
    const float* __restrict__ partials,
    float* __restrict__ out)
{
    const int tid = threadIdx.x;
    const int lane = tid & 63;
    const int wave = tid >> 6;  // 16 waves

    // Each thread sums 4 partials (stride-1024 for coalescing).
    float s = 0.0f;
    #pragma unroll
    for (int i = 0; i < 4; ++i)
        s += partials[tid + i * 1024];

    #pragma unroll
    for (int off = 32; off > 0; off >>= 1)
        s += __shfl_down(s, off, 64);

    __shared__ float wsum[16];
    if (lane == 0) wsum[wave] = s;
    __syncthreads();

    if (tid == 0) {
        float t = 0.0f;
        #pragma unroll
        for (int i = 0; i < 16; ++i) t += wsum[i];
        out[0] = t * (1.0f / (2.0f * BATCH));
    }
}

extern "C" void kernel_launch(void* const* d_in, const int* in_sizes, int n_in,
                              void* d_out, int out_size, void* d_ws, size_t ws_size,
                              hipStream_t stream) {
    const float* feat    = (const float*)d_in[0];
    const int*   labels  = (const int*)d_in[1];
    const float* centers = (const float*)d_in[2];
    float* out      = (float*)d_out;
    float* partials = (float*)d_ws;  // 4096 floats = 16 KB, fully rewritten each call

    center_loss_partial<<<NBLOCKS, 256, 0, stream>>>(feat, labels, centers, partials);
    center_loss_final<<<1, 1024, 0, stream>>>(partials, out);
}

// Round 3
// 11.893 us; speedup vs baseline: 5.3510x; 1.3399x over previous
//
#include <hip/hip_runtime.h>

#define BATCH 16384
#define FDIM 256
#define ROWS_PER_WAVE 4
#define WAVES_PER_BLOCK 4
#define NBLOCKS (BATCH / (ROWS_PER_WAVE * WAVES_PER_BLOCK))  // 1024 partials

__global__ __launch_bounds__(256) void center_loss_partial(
    const float* __restrict__ feat,
    const int* __restrict__ labels,
    const float* __restrict__ centers,
    float* __restrict__ partials)
{
    const int wave = threadIdx.x >> 6;
    const int lane = threadIdx.x & 63;
    // 4 consecutive rows per wave.
    const int row0 = (blockIdx.x * WAVES_PER_BLOCK + wave) * ROWS_PER_WAVE;

    // Wave-uniform label loads -> scalar loads, all issued up front.
    int lab[ROWS_PER_WAVE];
    #pragma unroll
    for (int r = 0; r < ROWS_PER_WAVE; ++r)
        lab[r] = labels[row0 + r];

    const float4* feat4 = reinterpret_cast<const float4*>(feat);
    const float4* cent4 = reinterpret_cast<const float4*>(centers);

    // 8 independent 16B loads per lane: maximize memory-level parallelism.
    float4 fv[ROWS_PER_WAVE], cv[ROWS_PER_WAVE];
    #pragma unroll
    for (int r = 0; r < ROWS_PER_WAVE; ++r)
        fv[r] = feat4[(size_t)(row0 + r) * 64 + lane];
    #pragma unroll
    for (int r = 0; r < ROWS_PER_WAVE; ++r)
        cv[r] = cent4[(size_t)lab[r] * 64 + lane];

    float s = 0.0f;
    #pragma unroll
    for (int r = 0; r < ROWS_PER_WAVE; ++r) {
        float dx = fv[r].x - cv[r].x;
        float dy = fv[r].y - cv[r].y;
        float dz = fv[r].z - cv[r].z;
        float dw = fv[r].w - cv[r].w;
        s += dx * dx + dy * dy + dz * dz + dw * dw;
    }

    // One wave-level reduction for all 4 rows.
    #pragma unroll
    for (int off = 32; off > 0; off >>= 1)
        s += __shfl_down(s, off, 64);

    __shared__ float wsum[WAVES_PER_BLOCK];
    if (lane == 0) wsum[wave] = s;
    __syncthreads();

    if (threadIdx.x == 0)
        partials[blockIdx.x] = (wsum[0] + wsum[1]) + (wsum[2] + wsum[3]);
}

__global__ __launch_bounds__(256) void center_loss_final(
    const float* __restrict__ partials,
    float* __restrict__ out)
{
    const int tid = threadIdx.x;
    const int lane = tid & 63;
    const int wave = tid >> 6;

    // 1024 partials = 256 float4: one coalesced 16B load per thread.
    float4 v = reinterpret_cast<const float4*>(partials)[tid];
    float s = (v.x + v.y) + (v.z + v.w);

    #pragma unroll
    for (int off = 32; off > 0; off >>= 1)
        s += __shfl_down(s, off, 64);

    __shared__ float wsum[4];
    if (lane == 0) wsum[wave] = s;
    __syncthreads();

    if (tid == 0) {
        float t = (wsum[0] + wsum[1]) + (wsum[2] + wsum[3]);
        out[0] = t * (1.0f / (2.0f * BATCH));
    }
}

extern "C" void kernel_launch(void* const* d_in, const int* in_sizes, int n_in,
                              void* d_out, int out_size, void* d_ws, size_t ws_size,
                              hipStream_t stream) {
    const float* feat    = (const float*)d_in[0];
    const int*   labels  = (const int*)d_in[1];
    const float* centers = (const float*)d_in[2];
    float* out      = (float*)d_out;
    float* partials = (float*)d_ws;  // 1024 floats, fully rewritten each call

    center_loss_partial<<<NBLOCKS, 256, 0, stream>>>(feat, labels, centers, partials);
    center_loss_final<<<1, 256, 0, stream>>>(partials, out);
}

// Round 4
// 11.624 us; speedup vs baseline: 5.4749x; 1.0232x over previous
//
#include <hip/hip_runtime.h>

#define BATCH 16384
#define FDIM 256
#define ROWS_PER_WAVE 8
#define WAVES_PER_BLOCK 4
#define NBLOCKS (BATCH / (ROWS_PER_WAVE * WAVES_PER_BLOCK))  // 512 partials

__global__ __launch_bounds__(256) void center_loss_partial(
    const float* __restrict__ feat,
    const int* __restrict__ labels,
    const float* __restrict__ centers,
    float* __restrict__ partials)
{
    const int wave = threadIdx.x >> 6;
    const int lane = threadIdx.x & 63;
    // 8 consecutive rows per wave; row base is wave-uniform.
    int row0 = (blockIdx.x * WAVES_PER_BLOCK + wave) * ROWS_PER_WAVE;
    // Tell the compiler it's uniform -> labels load becomes one s_load_dwordx8.
    row0 = __builtin_amdgcn_readfirstlane(row0);

    int lab[ROWS_PER_WAVE];
    #pragma unroll
    for (int r = 0; r < ROWS_PER_WAVE; ++r)
        lab[r] = labels[row0 + r];

    const float4* feat4 = reinterpret_cast<const float4*>(feat);
    const float4* cent4 = reinterpret_cast<const float4*>(centers);

    // 16 independent 16B loads per lane (8 feat + 8 center): deep MLP.
    float4 fv[ROWS_PER_WAVE], cv[ROWS_PER_WAVE];
    #pragma unroll
    for (int r = 0; r < ROWS_PER_WAVE; ++r)
        fv[r] = feat4[(size_t)(row0 + r) * 64 + lane];
    #pragma unroll
    for (int r = 0; r < ROWS_PER_WAVE; ++r)
        cv[r] = cent4[(size_t)lab[r] * 64 + lane];

    float s = 0.0f;
    #pragma unroll
    for (int r = 0; r < ROWS_PER_WAVE; ++r) {
        float dx = fv[r].x - cv[r].x;
        float dy = fv[r].y - cv[r].y;
        float dz = fv[r].z - cv[r].z;
        float dw = fv[r].w - cv[r].w;
        s += dx * dx + dy * dy + dz * dz + dw * dw;
    }

    // One wave-level reduction for all 8 rows.
    #pragma unroll
    for (int off = 32; off > 0; off >>= 1)
        s += __shfl_down(s, off, 64);

    __shared__ float wsum[WAVES_PER_BLOCK];
    if (lane == 0) wsum[wave] = s;
    __syncthreads();

    if (threadIdx.x == 0)
        partials[blockIdx.x] = (wsum[0] + wsum[1]) + (wsum[2] + wsum[3]);
}

// Single-wave final reduce: 512 partials = 64 lanes x 2 float4.
__global__ __launch_bounds__(64) void center_loss_final(
    const float* __restrict__ partials,
    float* __restrict__ out)
{
    const int lane = threadIdx.x;
    const float4* p4 = reinterpret_cast<const float4*>(partials);

    float4 a = p4[lane];
    float4 b = p4[lane + 64];
    float s = ((a.x + a.y) + (a.z + a.w)) + ((b.x + b.y) + (b.z + b.w));

    #pragma unroll
    for (int off = 32; off > 0; off >>= 1)
        s += __shfl_down(s, off, 64);

    if (lane == 0)
        out[0] = s * (1.0f / (2.0f * BATCH));
}

extern "C" void kernel_launch(void* const* d_in, const int* in_sizes, int n_in,
                              void* d_out, int out_size, void* d_ws, size_t ws_size,
                              hipStream_t stream) {
    const float* feat    = (const float*)d_in[0];
    const int*   labels  = (const int*)d_in[1];
    const float* centers = (const float*)d_in[2];
    float* out      = (float*)d_out;
    float* partials = (float*)d_ws;  // 512 floats, fully rewritten each call

    center_loss_partial<<<NBLOCKS, 256, 0, stream>>>(feat, labels, centers, partials);
    center_loss_final<<<1, 64, 0, stream>>>(partials, out);
}